// Round 1
// baseline (710.206 us; speedup 1.0000x reference)
//
#include <hip/hip_runtime.h>
#include <cstddef>

constexpr int cB = 8, cN = 8192, cM = 2048, cK = 16, cC = 128, cH = 64, cO = 256, cCH = 192;
constexpr int NPTS = cB * cM;        // 16384
constexpr int PPB  = 16;
constexpr int NBLK = NPTS / PPB;     // 1024
constexpr float cEPS = 1e-5f;

// ---- workspace layout (float offsets) ----
constexpr size_t ACC_BN1 = 0, ACC_BN2 = 128, ACC_STEM = 256, ACC_X1 = 768, ACC_X2 = 1280, ACC_FIN = 1792;
constexpr size_t SCL_BN1 = 2304, SCL_BN2 = 2432, SCL_STEM = 2560, SCL_X1 = 3072, SCL_X2 = 3584, SCL_FIN = 4096;
constexpr size_t OFF_SFT = 8192;                                  // s_feats transposed [B,N,C]
constexpr size_t OFF_TST = OFF_SFT + (size_t)cB * cN * cC;        // stem post-ELU [NPTS,256]
constexpr size_t OFF_Y1  = OFF_TST + (size_t)NPTS * 256;          // y1 post-ELU  [NPTS,256]
constexpr size_t OFF_Y2  = OFF_Y1  + (size_t)NPTS * 256;          // y2 post-ELU  [NPTS,256]
constexpr size_t OFF_DW  = OFF_Y2  + (size_t)NPTS * 256;          // dw matrix    [NPTS,192]
constexpr size_t WS_FLOATS = OFF_DW + (size_t)NPTS * cCH;         // ~24.1M floats = 96.5 MB

__device__ __forceinline__ float eluf(float x) { return x > 0.f ? x : expm1f(x); }

// ---- transpose s_feats [B,C,N] -> [B,N,C] ----
__global__ __launch_bounds__(256) void k_tr(const float* __restrict__ sf, float* __restrict__ sfT) {
    __shared__ float tile[32][33];
    int b = blockIdx.z, n0 = blockIdx.x * 32, c0 = blockIdx.y * 32;
    int tx = threadIdx.x, ty = threadIdx.y;
    #pragma unroll
    for (int j = 0; j < 32; j += 8)
        tile[ty + j][tx] = sf[((size_t)b * cC + (c0 + ty + j)) * cN + n0 + tx];
    __syncthreads();
    #pragma unroll
    for (int j = 0; j < 32; j += 8)
        sfT[((size_t)b * cN + (n0 + ty + j)) * cC + c0 + tx] = tile[tx][ty + j];
}

// ---- kA: BN1 (h1) stats + stem conv (store post-ELU) + stem stats ----
__global__ __launch_bounds__(256) void kA(const float* __restrict__ qp, const float* __restrict__ sp,
        const float* __restrict__ f1w, const float* __restrict__ f1b,
        const float* __restrict__ stw, const float* __restrict__ stb,
        const int* __restrict__ nidx, float* __restrict__ ws) {
    __shared__ float sw[256 * 49];
    __shared__ float al[48];
    __shared__ int   idx_s[16];
    __shared__ float red[128];
    int t = threadIdx.x;
    for (int l = t; l < 256 * 48; l += 256) sw[(l / 48) * 49 + (l % 48)] = stw[l];
    if (t < 128) red[t] = 0.f;
    int o = t & 63, kg = t >> 6;
    float w0 = f1w[o*3], w1 = f1w[o*3+1], w2 = f1w[o*3+2], fb = f1b[o];
    float sb = stb[t];
    float ps1 = 0, pss1 = 0, ps2 = 0, pss2 = 0;
    __syncthreads();
    for (int p = 0; p < PPB; p++) {
        int pt = blockIdx.x * PPB + p;
        int b = pt >> 11, m = pt & (cM - 1);
        if (t < 16) idx_s[t] = nidx[(size_t)pt * cK + t];
        __syncthreads();
        if (t < 48) { int c = t >> 4, k = t & 15;
            al[t] = sp[((size_t)b*3 + c)*cN + idx_s[k]] - qp[((size_t)b*3 + c)*cM + m]; }
        __syncthreads();
        #pragma unroll
        for (int i = 0; i < 4; i++) { int k = kg*4 + i;
            float v = fb + w0*al[k] + w1*al[16+k] + w2*al[32+k];
            float e = eluf(v); ps1 += e; pss1 += e*e; }
        float v = sb;
        #pragma unroll
        for (int j = 0; j < 48; j++) v += sw[t*49 + j] * al[j];
        float e = eluf(v); ps2 += e; pss2 += e*e;
        ws[OFF_TST + (size_t)pt*256 + t] = e;
    }
    atomicAdd(&red[o], ps1); atomicAdd(&red[64 + o], pss1);
    __syncthreads();
    if (t < 64) { atomicAdd(&ws[ACC_BN1 + t], red[t]); atomicAdd(&ws[ACC_BN1 + 64 + t], red[64 + t]); }
    atomicAdd(&ws[ACC_STEM + t], ps2); atomicAdd(&ws[ACC_STEM + 256 + t], pss2);
}

// ---- finalize: acc -> scale/shift ----
__global__ void kFin(float* ws, int accOff, int sclOff, const float* __restrict__ g,
                     const float* __restrict__ be, int Cn, float invCnt) {
    int i = threadIdx.x;
    if (i < Cn) {
        float mean = ws[accOff + i] * invCnt;
        float var  = ws[accOff + Cn + i] * invCnt - mean * mean;
        float s = g[i] * rsqrtf(var + cEPS);
        ws[sclOff + i] = s;
        ws[sclOff + Cn + i] = be[i] - mean * s;
    }
}

// ---- kC: recompute h1 (apply BN1), compute h2 pre-BN, BN2 stats ----
__global__ __launch_bounds__(256) void kC(const float* __restrict__ qp, const float* __restrict__ sp,
        const float* __restrict__ f1w, const float* __restrict__ f1b,
        const float* __restrict__ f2w, const float* __restrict__ f2b,
        const int* __restrict__ nidx, float* __restrict__ ws) {
    __shared__ float h1s[16 * 64];
    __shared__ float al[48];
    __shared__ int   idx_s[16];
    __shared__ float red[128];
    int t = threadIdx.x;
    if (t < 128) red[t] = 0.f;
    int o = t & 63, kg = t >> 6;
    float w0 = f1w[o*3], w1 = f1w[o*3+1], w2 = f1w[o*3+2], fb = f1b[o];
    float s1 = ws[SCL_BN1 + o], sh1 = ws[SCL_BN1 + 64 + o];
    float f2bv = f2b[o];
    float f2r[64];
    #pragma unroll
    for (int c = 0; c < 64; c++) f2r[c] = f2w[o*64 + c];
    float ps = 0, pss = 0;
    __syncthreads();
    for (int p = 0; p < PPB; p++) {
        int pt = blockIdx.x * PPB + p;
        int b = pt >> 11, m = pt & (cM - 1);
        if (t < 16) idx_s[t] = nidx[(size_t)pt * cK + t];
        __syncthreads();
        if (t < 48) { int c = t >> 4, k = t & 15;
            al[t] = sp[((size_t)b*3 + c)*cN + idx_s[k]] - qp[((size_t)b*3 + c)*cM + m]; }
        __syncthreads();
        #pragma unroll
        for (int i = 0; i < 4; i++) { int k = kg*4 + i;
            float v = fb + w0*al[k] + w1*al[16+k] + w2*al[32+k];
            h1s[k*64 + o] = s1 * eluf(v) + sh1; }
        __syncthreads();
        #pragma unroll
        for (int i = 0; i < 4; i++) { int k = kg*4 + i;
            float v = f2bv;
            #pragma unroll
            for (int c0 = 0; c0 < 64; c0 += 4) {
                float4 h = *(const float4*)&h1s[k*64 + c0];
                v += f2r[c0]*h.x + f2r[c0+1]*h.y + f2r[c0+2]*h.z + f2r[c0+3]*h.w;
            }
            float e = eluf(v); ps += e; pss += e*e; }
        __syncthreads();
    }
    atomicAdd(&red[o], ps); atomicAdd(&red[64 + o], pss);
    __syncthreads();
    if (t < 64) { atomicAdd(&ws[ACC_BN2 + t], red[t]); atomicAdd(&ws[ACC_BN2 + 64 + t], red[64 + t]); }
}

// ---- kE: stem(BN) -> conv x1 -> store y1 post-ELU + x1 stats ----
__global__ __launch_bounds__(256) void kE(const float* __restrict__ x1w, const float* __restrict__ x1b,
                                          float* __restrict__ ws) {
    __shared__ float xw[16 * 272];
    __shared__ float ts[256];
    int t = threadIdx.x;
    for (int l = t; l < 4096; l += 256) { int g = l >> 8, r = l & 255; xw[g*272 + (r>>4)*17 + (r&15)] = x1w[l]; }
    int g = t >> 4;
    float ss = ws[SCL_STEM + t], ssh = ws[SCL_STEM + 256 + t];
    float xb = x1b[t];
    int wbase = g*272 + (t & 15)*17;
    float ps = 0, pss = 0;
    __syncthreads();
    for (int p = 0; p < PPB; p++) {
        int pt = blockIdx.x * PPB + p;
        float e0 = ws[OFF_TST + (size_t)pt*256 + t];
        ts[t] = ss * e0 + ssh;
        __syncthreads();
        float v = xb;
        #pragma unroll
        for (int j = 0; j < 16; j++) v += ts[g*16 + j] * xw[wbase + j];
        float y = eluf(v); ps += y; pss += y*y;
        ws[OFF_Y1 + (size_t)pt*256 + t] = y;
        __syncthreads();
    }
    atomicAdd(&ws[ACC_X1 + t], ps); atomicAdd(&ws[ACC_X1 + 256 + t], pss);
}

// ---- kG: y1(BN_x1, with transpose reindex) -> conv x2 -> store y2 + x2 stats ----
__global__ __launch_bounds__(256) void kG(const float* __restrict__ x2w, const float* __restrict__ x2b,
                                          float* __restrict__ ws) {
    __shared__ float xw[16 * 272];
    __shared__ float ts[256];
    int t = threadIdx.x;
    for (int l = t; l < 4096; l += 256) { int g = l >> 8, r = l & 255; xw[g*272 + (r>>4)*17 + (r&15)] = x2w[l]; }
    int g = t >> 4;
    float sx = ws[SCL_X1 + t], shx = ws[SCL_X1 + 256 + t];
    float xb = x2b[t];
    int wbase = g*272 + (t & 15)*17;
    float ps = 0, pss = 0;
    __syncthreads();
    for (int p = 0; p < PPB; p++) {
        int pt = blockIdx.x * PPB + p;
        float e0 = ws[OFF_Y1 + (size_t)pt*256 + t];
        ts[t] = sx * e0 + shx;                 // ts indexed by y1 flat channel
        __syncthreads();
        float v = xb;
        #pragma unroll
        for (int j = 0; j < 16; j++) v += ts[j*16 + g] * xw[wbase + j];   // t_new[g,j] = y1bn[j*16+g]
        float y = eluf(v); ps += y; pss += y*y;
        ws[OFF_Y2 + (size_t)pt*256 + t] = y;
        __syncthreads();
    }
    atomicAdd(&ws[ACC_X2 + t], ps); atomicAdd(&ws[ACC_X2 + 256 + t], pss);
}

// ---- kI: main fused — gather nf, recompute h1/h2(BN), x from y2(BN_x2), qf, depthwise -> dw ----
__global__ __launch_bounds__(256) void kI(const float* __restrict__ qp, const float* __restrict__ sp,
        const float* __restrict__ f1w, const float* __restrict__ f1b,
        const float* __restrict__ f2w, const float* __restrict__ f2b,
        const float* __restrict__ dww, const int* __restrict__ nidx, float* __restrict__ ws) {
    __shared__ float h1s[16 * 64];
    __shared__ float nf[16 * 192];
    __shared__ float xs[256];
    __shared__ float al[48];
    __shared__ int   idx_s[16];
    int t = threadIdx.x;
    int o = t & 63, kg = t >> 6;
    float w0 = f1w[o*3], w1 = f1w[o*3+1], w2 = f1w[o*3+2], fb = f1b[o];
    float s1 = ws[SCL_BN1 + o],  sh1 = ws[SCL_BN1 + 64 + o];
    float s2 = ws[SCL_BN2 + o],  sh2 = ws[SCL_BN2 + 64 + o];
    float f2bv = f2b[o];
    float sx2 = ws[SCL_X2 + t], shx2 = ws[SCL_X2 + 256 + t];
    float f2r[64];
    #pragma unroll
    for (int c = 0; c < 64; c++) f2r[c] = f2w[o*64 + c];
    float dwr[16];
    #pragma unroll
    for (int l = 0; l < 16; l++) dwr[l] = (t < cCH) ? dww[t*16 + l] : 0.f;
    for (int p = 0; p < PPB; p++) {
        int pt = blockIdx.x * PPB + p;
        int b = pt >> 11, m = pt & (cM - 1);
        if (t < 16) idx_s[t] = nidx[(size_t)pt * cK + t];
        float e2 = ws[OFF_Y2 + (size_t)pt*256 + t];
        xs[t] = sx2 * e2 + shx2;               // x[k][l] at flat k*16+l
        __syncthreads();
        if (t < 48) { int c = t >> 4, k = t & 15;
            al[t] = sp[((size_t)b*3 + c)*cN + idx_s[k]] - qp[((size_t)b*3 + c)*cM + m]; }
        {
            int c = t & 127, kh = t >> 7;
            #pragma unroll
            for (int kk = 0; kk < 8; kk++) { int k = kk*2 + kh;
                nf[k*192 + c] = ws[OFF_SFT + ((size_t)b*cN + idx_s[k]) * cC + c]; }
        }
        __syncthreads();
        #pragma unroll
        for (int i = 0; i < 4; i++) { int k = kg*4 + i;
            float v = fb + w0*al[k] + w1*al[16+k] + w2*al[32+k];
            h1s[k*64 + o] = s1 * eluf(v) + sh1; }
        __syncthreads();
        #pragma unroll
        for (int i = 0; i < 4; i++) { int k = kg*4 + i;
            float v = f2bv;
            #pragma unroll
            for (int c0 = 0; c0 < 64; c0 += 4) {
                float4 h = *(const float4*)&h1s[k*64 + c0];
                v += f2r[c0]*h.x + f2r[c0+1]*h.y + f2r[c0+2]*h.z + f2r[c0+3]*h.w;
            }
            nf[k*192 + 128 + o] = s2 * eluf(v) + sh2; }
        __syncthreads();
        if (t < cCH) {
            float qa[16];
            #pragma unroll
            for (int l = 0; l < 16; l++) qa[l] = 0.f;
            #pragma unroll
            for (int k = 0; k < 16; k++) {
                float nfk = nf[k*192 + t];
                #pragma unroll
                for (int l4 = 0; l4 < 16; l4 += 4) {
                    float4 x4 = *(const float4*)&xs[k*16 + l4];
                    qa[l4]   += nfk * x4.x; qa[l4+1] += nfk * x4.y;
                    qa[l4+2] += nfk * x4.z; qa[l4+3] += nfk * x4.w;
                }
            }
            float dacc = 0;
            #pragma unroll
            for (int l = 0; l < 16; l++) dacc += qa[l] * dwr[l];
            ws[OFF_DW + (size_t)pt*cCH + t] = dacc;
        }
        __syncthreads();
    }
}

// ---- kJ: [16384x192]x[192x256] GEMM + bias + ELU + final stats, store to d_out ----
__global__ __launch_bounds__(256) void kJ(const float* __restrict__ pww, const float* __restrict__ pwb,
                                          float* __restrict__ ws, float* __restrict__ out) {
    __shared__ float As[16][65];
    __shared__ float Bs[16][65];
    int t = threadIdx.x;
    int tx = t & 15, ty = t >> 4;
    int p0 = blockIdx.x * 64, o0 = blockIdx.y * 64;
    float acc[4][4];
    #pragma unroll
    for (int i = 0; i < 4; i++)
        #pragma unroll
        for (int j = 0; j < 4; j++) acc[i][j] = 0.f;
    int la = t * 4;
    int apl = la >> 4, akl = la & 15;
    for (int kt = 0; kt < 12; kt++) {
        float4 av = *(const float4*)&ws[OFF_DW + (size_t)(p0 + apl)*cCH + kt*16 + akl];
        float4 bv = *(const float4*)&pww[(size_t)(o0 + apl)*cCH + kt*16 + akl];
        As[akl][apl] = av.x; As[akl+1][apl] = av.y; As[akl+2][apl] = av.z; As[akl+3][apl] = av.w;
        Bs[akl][apl] = bv.x; Bs[akl+1][apl] = bv.y; Bs[akl+2][apl] = bv.z; Bs[akl+3][apl] = bv.w;
        __syncthreads();
        #pragma unroll
        for (int kk = 0; kk < 16; kk++) {
            float a0 = As[kk][tx*4], a1 = As[kk][tx*4+1], a2 = As[kk][tx*4+2], a3 = As[kk][tx*4+3];
            float b0 = Bs[kk][ty*4], b1 = Bs[kk][ty*4+1], b2 = Bs[kk][ty*4+2], b3 = Bs[kk][ty*4+3];
            acc[0][0]+=a0*b0; acc[0][1]+=a0*b1; acc[0][2]+=a0*b2; acc[0][3]+=a0*b3;
            acc[1][0]+=a1*b0; acc[1][1]+=a1*b1; acc[1][2]+=a1*b2; acc[1][3]+=a1*b3;
            acc[2][0]+=a2*b0; acc[2][1]+=a2*b1; acc[2][2]+=a2*b2; acc[2][3]+=a2*b3;
            acc[3][0]+=a3*b0; acc[3][1]+=a3*b1; acc[3][2]+=a3*b2; acc[3][3]+=a3*b3;
        }
        __syncthreads();
    }
    int b = p0 >> 11, mb = (p0 & (cM - 1)) + tx*4;
    #pragma unroll
    for (int j = 0; j < 4; j++) {
        int oo = o0 + ty*4 + j;
        float pb = pwb[oo];
        float e0 = eluf(acc[0][j] + pb), e1 = eluf(acc[1][j] + pb);
        float e2 = eluf(acc[2][j] + pb), e3 = eluf(acc[3][j] + pb);
        float sum = e0+e1+e2+e3, ssq = e0*e0+e1*e1+e2*e2+e3*e3;
        #pragma unroll
        for (int off = 1; off < 16; off <<= 1) { sum += __shfl_xor(sum, off); ssq += __shfl_xor(ssq, off); }
        if (tx == 0) { atomicAdd(&ws[ACC_FIN + oo], sum); atomicAdd(&ws[ACC_FIN + 256 + oo], ssq); }
        float4 st = make_float4(e0, e1, e2, e3);
        *(float4*)&out[((size_t)b*cO + oo)*cM + mb] = st;
    }
}

// ---- kK: apply final BN affine in-place on d_out ----
__global__ __launch_bounds__(256) void kK(float* __restrict__ out, const float* __restrict__ ws) {
    int i = blockIdx.x * 256 + threadIdx.x;
    if (i < (cB*cO*cM) / 4) {
        int o = (i >> 9) & 255;
        float s = ws[SCL_FIN + o], sh = ws[SCL_FIN + 256 + o];
        float4 v = ((float4*)out)[i];
        v.x = s*v.x + sh; v.y = s*v.y + sh; v.z = s*v.z + sh; v.w = s*v.w + sh;
        ((float4*)out)[i] = v;
    }
}

extern "C" void kernel_launch(void* const* d_in, const int* in_sizes, int n_in,
                              void* d_out, int out_size, void* d_ws, size_t ws_size,
                              hipStream_t stream) {
    const float* qp   = (const float*)d_in[0];
    const float* sp   = (const float*)d_in[1];
    const float* sf   = (const float*)d_in[2];
    const float* f1w  = (const float*)d_in[3];
    const float* f1b  = (const float*)d_in[4];
    const float* f1g  = (const float*)d_in[5];
    const float* f1be = (const float*)d_in[6];
    const float* f2w  = (const float*)d_in[7];
    const float* f2b  = (const float*)d_in[8];
    const float* f2g  = (const float*)d_in[9];
    const float* f2be = (const float*)d_in[10];
    const float* stw  = (const float*)d_in[11];
    const float* stb  = (const float*)d_in[12];
    const float* stg  = (const float*)d_in[13];
    const float* stbe = (const float*)d_in[14];
    const float* x1w  = (const float*)d_in[15];
    const float* x1b  = (const float*)d_in[16];
    const float* x1g  = (const float*)d_in[17];
    const float* x1be = (const float*)d_in[18];
    const float* x2w  = (const float*)d_in[19];
    const float* x2b  = (const float*)d_in[20];
    const float* x2g  = (const float*)d_in[21];
    const float* x2be = (const float*)d_in[22];
    const float* dww  = (const float*)d_in[23];
    const float* pww  = (const float*)d_in[24];
    const float* pwb  = (const float*)d_in[25];
    const float* sepg = (const float*)d_in[26];
    const float* sepbe= (const float*)d_in[27];
    const int*   nidx = (const int*)d_in[28];
    float* ws  = (float*)d_ws;
    float* out = (float*)d_out;
    if (ws_size < WS_FLOATS * sizeof(float)) return;  // insufficient scratch -> visible failure

    hipMemsetAsync(d_ws, 0, 2304 * sizeof(float), stream);  // zero stat accumulators (poisoned otherwise)
    k_tr<<<dim3(cN/32, cC/32, cB), dim3(32, 8), 0, stream>>>(sf, ws + OFF_SFT);
    kA<<<NBLK, 256, 0, stream>>>(qp, sp, f1w, f1b, stw, stb, nidx, ws);
    kFin<<<1, 64,  0, stream>>>(ws, (int)ACC_BN1,  (int)SCL_BN1,  f1g, f1be, 64,  1.f/262144.f);
    kFin<<<1, 256, 0, stream>>>(ws, (int)ACC_STEM, (int)SCL_STEM, stg, stbe, 256, 1.f/16384.f);
    kC<<<NBLK, 256, 0, stream>>>(qp, sp, f1w, f1b, f2w, f2b, nidx, ws);
    kFin<<<1, 64,  0, stream>>>(ws, (int)ACC_BN2,  (int)SCL_BN2,  f2g, f2be, 64,  1.f/262144.f);
    kE<<<NBLK, 256, 0, stream>>>(x1w, x1b, ws);
    kFin<<<1, 256, 0, stream>>>(ws, (int)ACC_X1,   (int)SCL_X1,   x1g, x1be, 256, 1.f/16384.f);
    kG<<<NBLK, 256, 0, stream>>>(x2w, x2b, ws);
    kFin<<<1, 256, 0, stream>>>(ws, (int)ACC_X2,   (int)SCL_X2,   x2g, x2be, 256, 1.f/16384.f);
    kI<<<NBLK, 256, 0, stream>>>(qp, sp, f1w, f1b, f2w, f2b, dww, nidx, ws);
    kJ<<<dim3(NPTS/64, cO/64), 256, 0, stream>>>(pww, pwb, ws, out);
    kFin<<<1, 256, 0, stream>>>(ws, (int)ACC_FIN,  (int)SCL_FIN,  sepg, sepbe, 256, 1.f/16384.f);
    kK<<<(cB*cO*cM/4 + 255)/256, 256, 0, stream>>>(out, ws);
}

// Round 2
// 447.631 us; speedup vs baseline: 1.5866x; 1.5866x over previous
//
#include <hip/hip_runtime.h>
#include <hip/hip_bf16.h>
#include <cstddef>

constexpr int cB = 8, cN = 8192, cM = 2048, cK = 16, cC = 128, cH = 64, cO = 256, cCH = 192;
constexpr int NPTS = cB * cM;        // 16384
constexpr int PPB  = 16;
constexpr int NBLK = NPTS / PPB;     // 1024
constexpr int PPB_I = 8;
constexpr int NBLK_I = NPTS / PPB_I; // 2048
constexpr float cEPS = 1e-5f;

// ---- workspace layout (float offsets) ----
constexpr size_t ACC_BN1 = 0, ACC_BN2 = 128, ACC_STEM = 256, ACC_X1 = 768, ACC_X2 = 1280, ACC_FIN = 1792;
constexpr size_t SCL_BN1 = 2304, SCL_BN2 = 2432, SCL_STEM = 2560, SCL_X1 = 3072, SCL_X2 = 3584, SCL_FIN = 4096;
constexpr size_t OFF_SFT = 8192;                                  // s_feats transposed [B,N,C] f32
constexpr size_t OFF_TST = OFF_SFT + (size_t)cB * cN * cC;        // stem post-ELU [NPTS,256] f32; later h2 bf16 [NPTS,16,64] (spans TST+Y1)
constexpr size_t OFF_Y1  = OFF_TST + (size_t)NPTS * 256;          // y1 post-ELU  [NPTS,256] f32
constexpr size_t OFF_Y2  = OFF_Y1  + (size_t)NPTS * 256;          // y2 post-ELU  [NPTS,256] f32
constexpr size_t OFF_DW  = OFF_Y2  + (size_t)NPTS * 256;          // dw matrix    [NPTS,192] f32
constexpr size_t WS_FLOATS = OFF_DW + (size_t)NPTS * cCH;         // ~24.1M floats = 96.5 MB

__device__ __forceinline__ float eluf(float x) { return x > 0.f ? x : expm1f(x); }

// ---- transpose s_feats [B,C,N] -> [B,N,C] ----
__global__ __launch_bounds__(256) void k_tr(const float* __restrict__ sf, float* __restrict__ sfT) {
    __shared__ float tile[32][33];
    int b = blockIdx.z, n0 = blockIdx.x * 32, c0 = blockIdx.y * 32;
    int tx = threadIdx.x, ty = threadIdx.y;
    #pragma unroll
    for (int j = 0; j < 32; j += 8)
        tile[ty + j][tx] = sf[((size_t)b * cC + (c0 + ty + j)) * cN + n0 + tx];
    __syncthreads();
    #pragma unroll
    for (int j = 0; j < 32; j += 8)
        sfT[((size_t)b * cN + (n0 + ty + j)) * cC + c0 + tx] = tile[tx][ty + j];
}

// ---- kA: BN1 (h1) stats + stem conv (store post-ELU) + stem stats ----
__global__ __launch_bounds__(256) void kA(const float* __restrict__ qp, const float* __restrict__ sp,
        const float* __restrict__ f1w, const float* __restrict__ f1b,
        const float* __restrict__ stw, const float* __restrict__ stb,
        const int* __restrict__ nidx, float* __restrict__ ws) {
    __shared__ float sw[256 * 49];
    __shared__ float al[48];
    __shared__ int   idx_s[256];
    __shared__ float red[128];
    int t = threadIdx.x;
    for (int l = t; l < 256 * 48; l += 256) sw[(l / 48) * 49 + (l % 48)] = stw[l];
    if (t < 128) red[t] = 0.f;
    idx_s[t] = nidx[(size_t)blockIdx.x * 256 + t];
    int o = t & 63, kg = t >> 6;
    float w0 = f1w[o*3], w1 = f1w[o*3+1], w2 = f1w[o*3+2], fb = f1b[o];
    float sb = stb[t];
    float ps1 = 0, pss1 = 0, ps2 = 0, pss2 = 0;
    __syncthreads();
    for (int p = 0; p < PPB; p++) {
        int pt = blockIdx.x * PPB + p;
        int b = pt >> 11, m = pt & (cM - 1);
        if (t < 48) { int c = t >> 4, k = t & 15;
            al[t] = sp[((size_t)b*3 + c)*cN + idx_s[p*16 + k]] - qp[((size_t)b*3 + c)*cM + m]; }
        __syncthreads();
        #pragma unroll
        for (int i = 0; i < 4; i++) { int k = kg*4 + i;
            float v = fb + w0*al[k] + w1*al[16+k] + w2*al[32+k];
            float e = eluf(v); ps1 += e; pss1 += e*e; }
        float v = sb;
        #pragma unroll
        for (int j = 0; j < 48; j++) v += sw[t*49 + j] * al[j];
        float e = eluf(v); ps2 += e; pss2 += e*e;
        ws[OFF_TST + (size_t)pt*256 + t] = e;
        __syncthreads();
    }
    atomicAdd(&red[o], ps1); atomicAdd(&red[64 + o], pss1);
    __syncthreads();
    if (t < 64) { atomicAdd(&ws[ACC_BN1 + t], red[t]); atomicAdd(&ws[ACC_BN1 + 64 + t], red[64 + t]); }
    atomicAdd(&ws[ACC_STEM + t], ps2); atomicAdd(&ws[ACC_STEM + 256 + t], pss2);
}

// ---- finalize: acc -> scale/shift ----
__global__ void kFin(float* ws, int accOff, int sclOff, const float* __restrict__ g,
                     const float* __restrict__ be, int Cn, float invCnt) {
    int i = threadIdx.x;
    if (i < Cn) {
        float mean = ws[accOff + i] * invCnt;
        float var  = ws[accOff + Cn + i] * invCnt - mean * mean;
        float s = g[i] * rsqrtf(var + cEPS);
        ws[sclOff + i] = s;
        ws[sclOff + Cn + i] = be[i] - mean * s;
    }
}

// ---- kC: recompute h1 (apply BN1), compute h2 post-ELU -> store bf16 + BN2 stats ----
__global__ __launch_bounds__(256) void kC(const float* __restrict__ qp, const float* __restrict__ sp,
        const float* __restrict__ f1w, const float* __restrict__ f1b,
        const float* __restrict__ f2w, const float* __restrict__ f2b,
        const int* __restrict__ nidx, float* __restrict__ ws) {
    __shared__ float h1s[16 * 64];
    __shared__ float al[48];
    __shared__ int   idx_s[256];
    __shared__ float red[128];
    __hip_bfloat16* h2b = (__hip_bfloat16*)(ws + OFF_TST);
    int t = threadIdx.x;
    if (t < 128) red[t] = 0.f;
    idx_s[t] = nidx[(size_t)blockIdx.x * 256 + t];
    int o = t & 63, kg = t >> 6;
    float w0 = f1w[o*3], w1 = f1w[o*3+1], w2 = f1w[o*3+2], fb = f1b[o];
    float s1 = ws[SCL_BN1 + o], sh1 = ws[SCL_BN1 + 64 + o];
    float f2bv = f2b[o];
    float f2r[64];
    #pragma unroll
    for (int c = 0; c < 64; c++) f2r[c] = f2w[o*64 + c];
    float ps = 0, pss = 0;
    __syncthreads();
    for (int p = 0; p < PPB; p++) {
        int pt = blockIdx.x * PPB + p;
        int b = pt >> 11, m = pt & (cM - 1);
        if (t < 48) { int c = t >> 4, k = t & 15;
            al[t] = sp[((size_t)b*3 + c)*cN + idx_s[p*16 + k]] - qp[((size_t)b*3 + c)*cM + m]; }
        __syncthreads();
        #pragma unroll
        for (int i = 0; i < 4; i++) { int k = kg*4 + i;
            float v = fb + w0*al[k] + w1*al[16+k] + w2*al[32+k];
            h1s[k*64 + o] = s1 * eluf(v) + sh1; }
        __syncthreads();
        #pragma unroll
        for (int i = 0; i < 4; i++) { int k = kg*4 + i;
            float v = f2bv;
            #pragma unroll
            for (int c0 = 0; c0 < 64; c0 += 4) {
                float4 h = *(const float4*)&h1s[k*64 + c0];
                v += f2r[c0]*h.x + f2r[c0+1]*h.y + f2r[c0+2]*h.z + f2r[c0+3]*h.w;
            }
            float e = eluf(v); ps += e; pss += e*e;
            h2b[(size_t)pt*1024 + (size_t)k*64 + o] = __float2bfloat16(e); }
    }
    atomicAdd(&red[o], ps); atomicAdd(&red[64 + o], pss);
    __syncthreads();
    if (t < 64) { atomicAdd(&ws[ACC_BN2 + t], red[t]); atomicAdd(&ws[ACC_BN2 + 64 + t], red[64 + t]); }
}

// ---- kE: stem(BN) -> conv x1 -> store y1 post-ELU + x1 stats ----
__global__ __launch_bounds__(256) void kE(const float* __restrict__ x1w, const float* __restrict__ x1b,
                                          float* __restrict__ ws) {
    __shared__ float xw[16 * 272];
    __shared__ float ts[256];
    int t = threadIdx.x;
    for (int l = t; l < 4096; l += 256) { int g = l >> 8, r = l & 255; xw[g*272 + (r>>4)*17 + (r&15)] = x1w[l]; }
    int g = t >> 4;
    float ss = ws[SCL_STEM + t], ssh = ws[SCL_STEM + 256 + t];
    float xb = x1b[t];
    int wbase = g*272 + (t & 15)*17;
    float ps = 0, pss = 0;
    __syncthreads();
    for (int p = 0; p < PPB; p++) {
        int pt = blockIdx.x * PPB + p;
        float e0 = ws[OFF_TST + (size_t)pt*256 + t];
        ts[t] = ss * e0 + ssh;
        __syncthreads();
        float v = xb;
        #pragma unroll
        for (int j = 0; j < 16; j++) v += ts[g*16 + j] * xw[wbase + j];
        float y = eluf(v); ps += y; pss += y*y;
        ws[OFF_Y1 + (size_t)pt*256 + t] = y;
        __syncthreads();
    }
    atomicAdd(&ws[ACC_X1 + t], ps); atomicAdd(&ws[ACC_X1 + 256 + t], pss);
}

// ---- kG: y1(BN_x1, with transpose reindex) -> conv x2 -> store y2 + x2 stats ----
__global__ __launch_bounds__(256) void kG(const float* __restrict__ x2w, const float* __restrict__ x2b,
                                          float* __restrict__ ws) {
    __shared__ float xw[16 * 272];
    __shared__ float ts[256];
    int t = threadIdx.x;
    for (int l = t; l < 4096; l += 256) { int g = l >> 8, r = l & 255; xw[g*272 + (r>>4)*17 + (r&15)] = x2w[l]; }
    int g = t >> 4;
    float sx = ws[SCL_X1 + t], shx = ws[SCL_X1 + 256 + t];
    float xb = x2b[t];
    int wbase = g*272 + (t & 15)*17;
    float ps = 0, pss = 0;
    __syncthreads();
    for (int p = 0; p < PPB; p++) {
        int pt = blockIdx.x * PPB + p;
        float e0 = ws[OFF_Y1 + (size_t)pt*256 + t];
        ts[t] = sx * e0 + shx;                 // ts indexed by y1 flat channel
        __syncthreads();
        float v = xb;
        #pragma unroll
        for (int j = 0; j < 16; j++) v += ts[j*16 + g] * xw[wbase + j];   // t_new[g,j] = y1bn[j*16+g]
        float y = eluf(v); ps += y; pss += y*y;
        ws[OFF_Y2 + (size_t)pt*256 + t] = y;
        __syncthreads();
    }
    atomicAdd(&ws[ACC_X2 + t], ps); atomicAdd(&ws[ACC_X2 + 256 + t], pss);
}

// ---- kI: gather nf + load h2(bf16,BN2) + x from y2(BN_x2) -> qf -> depthwise -> dw ----
__global__ __launch_bounds__(256) void kI(const float* __restrict__ dww,
        const int* __restrict__ nidx, float* __restrict__ ws) {
    __shared__ float nf[16 * 192];
    __shared__ float xs[256];
    __shared__ int   idx_s[PPB_I * 16];
    const __hip_bfloat16* h2b = (const __hip_bfloat16*)(ws + OFF_TST);
    int t = threadIdx.x;
    int o = t & 63;
    float s2 = ws[SCL_BN2 + o],  sh2 = ws[SCL_BN2 + 64 + o];
    float sx2 = ws[SCL_X2 + t], shx2 = ws[SCL_X2 + 256 + t];
    float dwr[16];
    #pragma unroll
    for (int l = 0; l < 16; l++) dwr[l] = (t < cCH) ? dww[t*16 + l] : 0.f;
    if (t < PPB_I * 16) idx_s[t] = nidx[(size_t)blockIdx.x * (PPB_I*16) + t];
    __syncthreads();
    for (int p = 0; p < PPB_I; p++) {
        int pt = blockIdx.x * PPB_I + p;
        int b = pt >> 11;
        float e2 = ws[OFF_Y2 + (size_t)pt*256 + t];
        xs[t] = sx2 * e2 + shx2;               // x[k][l] at flat k*16+l
        #pragma unroll
        for (int kk = 0; kk < 4; kk++) {
            float hv = __bfloat162float(h2b[(size_t)pt*1024 + kk*256 + t]);
            int k = (kk*256 + t) >> 6;
            nf[k*192 + 128 + o] = s2 * hv + sh2;
        }
        {
            int c = t & 127, kh = t >> 7;
            #pragma unroll
            for (int kk = 0; kk < 8; kk++) { int k = kk*2 + kh;
                nf[k*192 + c] = ws[OFF_SFT + ((size_t)b*cN + idx_s[p*16 + k]) * cC + c]; }
        }
        __syncthreads();
        if (t < cCH) {
            float qa[16];
            #pragma unroll
            for (int l = 0; l < 16; l++) qa[l] = 0.f;
            #pragma unroll
            for (int k = 0; k < 16; k++) {
                float nfk = nf[k*192 + t];
                #pragma unroll
                for (int l4 = 0; l4 < 16; l4 += 4) {
                    float4 x4 = *(const float4*)&xs[k*16 + l4];
                    qa[l4]   += nfk * x4.x; qa[l4+1] += nfk * x4.y;
                    qa[l4+2] += nfk * x4.z; qa[l4+3] += nfk * x4.w;
                }
            }
            float dacc = 0;
            #pragma unroll
            for (int l = 0; l < 16; l++) dacc += qa[l] * dwr[l];
            ws[OFF_DW + (size_t)pt*cCH + t] = dacc;
        }
        __syncthreads();
    }
}

// ---- kJ: [16384x192]x[192x256] GEMM + bias + ELU + final stats, store to d_out ----
__global__ __launch_bounds__(256) void kJ(const float* __restrict__ pww, const float* __restrict__ pwb,
                                          float* __restrict__ ws, float* __restrict__ out) {
    __shared__ float As[16][65];
    __shared__ float Bs[16][65];
    int t = threadIdx.x;
    int tx = t & 15, ty = t >> 4;
    int p0 = blockIdx.x * 64, o0 = blockIdx.y * 64;
    float acc[4][4];
    #pragma unroll
    for (int i = 0; i < 4; i++)
        #pragma unroll
        for (int j = 0; j < 4; j++) acc[i][j] = 0.f;
    int la = t * 4;
    int apl = la >> 4, akl = la & 15;
    for (int kt = 0; kt < 12; kt++) {
        float4 av = *(const float4*)&ws[OFF_DW + (size_t)(p0 + apl)*cCH + kt*16 + akl];
        float4 bv = *(const float4*)&pww[(size_t)(o0 + apl)*cCH + kt*16 + akl];
        As[akl][apl] = av.x; As[akl+1][apl] = av.y; As[akl+2][apl] = av.z; As[akl+3][apl] = av.w;
        Bs[akl][apl] = bv.x; Bs[akl+1][apl] = bv.y; Bs[akl+2][apl] = bv.z; Bs[akl+3][apl] = bv.w;
        __syncthreads();
        #pragma unroll
        for (int kk = 0; kk < 16; kk++) {
            float a0 = As[kk][tx*4], a1 = As[kk][tx*4+1], a2 = As[kk][tx*4+2], a3 = As[kk][tx*4+3];
            float b0 = Bs[kk][ty*4], b1 = Bs[kk][ty*4+1], b2 = Bs[kk][ty*4+2], b3 = Bs[kk][ty*4+3];
            acc[0][0]+=a0*b0; acc[0][1]+=a0*b1; acc[0][2]+=a0*b2; acc[0][3]+=a0*b3;
            acc[1][0]+=a1*b0; acc[1][1]+=a1*b1; acc[1][2]+=a1*b2; acc[1][3]+=a1*b3;
            acc[2][0]+=a2*b0; acc[2][1]+=a2*b1; acc[2][2]+=a2*b2; acc[2][3]+=a2*b3;
            acc[3][0]+=a3*b0; acc[3][1]+=a3*b1; acc[3][2]+=a3*b2; acc[3][3]+=a3*b3;
        }
        __syncthreads();
    }
    int b = p0 >> 11, mb = (p0 & (cM - 1)) + tx*4;
    #pragma unroll
    for (int j = 0; j < 4; j++) {
        int oo = o0 + ty*4 + j;
        float pb = pwb[oo];
        float e0 = eluf(acc[0][j] + pb), e1 = eluf(acc[1][j] + pb);
        float e2 = eluf(acc[2][j] + pb), e3 = eluf(acc[3][j] + pb);
        float sum = e0+e1+e2+e3, ssq = e0*e0+e1*e1+e2*e2+e3*e3;
        #pragma unroll
        for (int off = 1; off < 16; off <<= 1) { sum += __shfl_xor(sum, off); ssq += __shfl_xor(ssq, off); }
        if (tx == 0) { atomicAdd(&ws[ACC_FIN + oo], sum); atomicAdd(&ws[ACC_FIN + 256 + oo], ssq); }
        float4 st = make_float4(e0, e1, e2, e3);
        *(float4*)&out[((size_t)b*cO + oo)*cM + mb] = st;
    }
}

// ---- kK: apply final BN affine in-place on d_out ----
__global__ __launch_bounds__(256) void kK(float* __restrict__ out, const float* __restrict__ ws) {
    int i = blockIdx.x * 256 + threadIdx.x;
    if (i < (cB*cO*cM) / 4) {
        int o = (i >> 9) & 255;
        float s = ws[SCL_FIN + o], sh = ws[SCL_FIN + 256 + o];
        float4 v = ((float4*)out)[i];
        v.x = s*v.x + sh; v.y = s*v.y + sh; v.z = s*v.z + sh; v.w = s*v.w + sh;
        ((float4*)out)[i] = v;
    }
}

extern "C" void kernel_launch(void* const* d_in, const int* in_sizes, int n_in,
                              void* d_out, int out_size, void* d_ws, size_t ws_size,
                              hipStream_t stream) {
    const float* qp   = (const float*)d_in[0];
    const float* sp   = (const float*)d_in[1];
    const float* sf   = (const float*)d_in[2];
    const float* f1w  = (const float*)d_in[3];
    const float* f1b  = (const float*)d_in[4];
    const float* f1g  = (const float*)d_in[5];
    const float* f1be = (const float*)d_in[6];
    const float* f2w  = (const float*)d_in[7];
    const float* f2b  = (const float*)d_in[8];
    const float* f2g  = (const float*)d_in[9];
    const float* f2be = (const float*)d_in[10];
    const float* stw  = (const float*)d_in[11];
    const float* stb  = (const float*)d_in[12];
    const float* stg  = (const float*)d_in[13];
    const float* stbe = (const float*)d_in[14];
    const float* x1w  = (const float*)d_in[15];
    const float* x1b  = (const float*)d_in[16];
    const float* x1g  = (const float*)d_in[17];
    const float* x1be = (const float*)d_in[18];
    const float* x2w  = (const float*)d_in[19];
    const float* x2b  = (const float*)d_in[20];
    const float* x2g  = (const float*)d_in[21];
    const float* x2be = (const float*)d_in[22];
    const float* dww  = (const float*)d_in[23];
    const float* pww  = (const float*)d_in[24];
    const float* pwb  = (const float*)d_in[25];
    const float* sepg = (const float*)d_in[26];
    const float* sepbe= (const float*)d_in[27];
    const int*   nidx = (const int*)d_in[28];
    float* ws  = (float*)d_ws;
    float* out = (float*)d_out;
    if (ws_size < WS_FLOATS * sizeof(float)) return;  // insufficient scratch -> visible failure

    hipMemsetAsync(d_ws, 0, 2304 * sizeof(float), stream);  // zero stat accumulators (poisoned otherwise)
    k_tr<<<dim3(cN/32, cC/32, cB), dim3(32, 8), 0, stream>>>(sf, ws + OFF_SFT);
    kA<<<NBLK, 256, 0, stream>>>(qp, sp, f1w, f1b, stw, stb, nidx, ws);
    kFin<<<1, 64,  0, stream>>>(ws, (int)ACC_BN1,  (int)SCL_BN1,  f1g, f1be, 64,  1.f/262144.f);
    kFin<<<1, 256, 0, stream>>>(ws, (int)ACC_STEM, (int)SCL_STEM, stg, stbe, 256, 1.f/16384.f);
    kE<<<NBLK, 256, 0, stream>>>(x1w, x1b, ws);
    kFin<<<1, 256, 0, stream>>>(ws, (int)ACC_X1,   (int)SCL_X1,   x1g, x1be, 256, 1.f/16384.f);
    kG<<<NBLK, 256, 0, stream>>>(x2w, x2b, ws);
    kFin<<<1, 256, 0, stream>>>(ws, (int)ACC_X2,   (int)SCL_X2,   x2g, x2be, 256, 1.f/16384.f);
    // kC runs after kE/kG: it overwrites TST (+Y1) with bf16 h2 once those are consumed
    kC<<<NBLK, 256, 0, stream>>>(qp, sp, f1w, f1b, f2w, f2b, nidx, ws);
    kFin<<<1, 64,  0, stream>>>(ws, (int)ACC_BN2,  (int)SCL_BN2,  f2g, f2be, 64,  1.f/262144.f);
    kI<<<NBLK_I, 256, 0, stream>>>(dww, nidx, ws);
    kJ<<<dim3(NPTS/64, cO/64), 256, 0, stream>>>(pww, pwb, ws, out);
    kFin<<<1, 256, 0, stream>>>(ws, (int)ACC_FIN,  (int)SCL_FIN,  sepg, sepbe, 256, 1.f/16384.f);
    kK<<<(cB*cO*cM/4 + 255)/256, 256, 0, stream>>>(out, ws);
}